// Round 7
// baseline (140.123 us; speedup 1.0000x reference)
//
#include <hip/hip_runtime.h>

// BNMorph forward — fully fused: per-tile point re-derivation + gather-splat.
// B=8, H=320, W=1024. Outputs (concat, f32, each [B,H,W]):
//   0 morphedx, 1 morphedy, 2 orgpts_x, 3 orgpts_y, 4 correspts_x, 5 correspts_y

#define BB 8
#define HH 320
#define WW 1024
#define N_PIX (BB*HH*WW)            // 2,621,440
#define WPI (HH*(WW/32))            // 10240 words per image
#define RR 20
#define TLW 64
#define TLH 32
#define TXN (WW/TLW)                // 16
#define TYN (HH/TLH)                // 10
#define NQ 105
#define CAP 192                     // per-tile candidate capacity (mean ~103)
#define WTABN (4*42*48)             // 8064 floats
#define WTAB_OFF (2*BB*WPI*4)       // 655360 (16B aligned)

typedef unsigned long long u64;
typedef float v2f __attribute__((ext_vector_type(2)));

// ---- kernel 1: pack maps to bitmasks + build rotated weight table ----
__global__ __launch_bounds__(256) void pack_zero(
    const float* __restrict__ src, const float* __restrict__ dst,
    unsigned* __restrict__ packed, float* __restrict__ wtab_g)
{
    int t = threadIdx.x;
    int i = blockIdx.x * 256 + t;           // float4 index in [0, 2*N_PIX/4)
    if (i < WTABN) {                        // rotated-padded weight table
        int rot = i / (42 * 48);
        int rem = i - rot * (42 * 48);
        int row = rem / 48, c = rem - row * 48;
        int pc = c + rot;
        float v = 0.0f;
        if (row <= 40 && pc >= 4 && pc <= 44) {
            int dxv = pc - 24, dyv = row - 20;
            float d = sqrtf((float)(dxv * dxv + dyv * dyv));
            v = 0.7f * expf((-d * 1.9f) / 24.0f);
        }
        wtab_g[i] = v;
    }
    const float4* p = (i < (N_PIX >> 2)) ? (const float4*)src + i
                                         : (const float4*)dst + (i - (N_PIX >> 2));
    float4 v = *p;
    unsigned nib = (v.x > 0.5f ? 1u : 0u) | (v.y > 0.5f ? 2u : 0u)
                 | (v.z > 0.5f ? 4u : 0u) | (v.w > 0.5f ? 8u : 0u);
    unsigned val = nib << ((t & 7) * 4);
    val |= __shfl_xor(val, 1);
    val |= __shfl_xor(val, 2);
    val |= __shfl_xor(val, 4);
    if ((t & 7) == 0) packed[i >> 3] = val;
}

// ---- kernel 2: fused point-finding + splat + all dense writes ----
// One block per 64x32 tile. grid (16, 10, 8).
__global__ __launch_bounds__(256, 4) void fused_morph(
    const unsigned* __restrict__ packed,
    const float* __restrict__ xx, const float* __restrict__ yy,
    const float* __restrict__ wtab_g,
    float* __restrict__ out)
{
    __shared__ __align__(16) float wtab[WTABN];      // 32.25 KB
    __shared__ unsigned sSrc[74][6];   // rows ty0-22..ty0+51, words wb0-1+{0..5}, pads at 0,5
    __shared__ unsigned sDst[78][6];   // rows ty0-23..ty0+54
    __shared__ __align__(16) unsigned sPt[CAP];      // candidates -> packed points
    __shared__ int prank[NQ];          // window pos -> (rank<<8)|((dx+7)<<4)|(dy+3)
    __shared__ unsigned char sVB[TLH * TLW];         // in-tile 0x80|vxp7|(vyp3<<4)
    __shared__ int lcnt;

    int t = threadIdx.x;
    int txT = blockIdx.x, tyT = blockIdx.y, b = blockIdx.z;
    int tx0 = txT * TLW, ty0 = tyT * TLH;
    int wb0 = (tx0 >> 5) - 1;          // global word of LDS word index 1
    const unsigned* psrc = packed + (size_t)b * WPI;
    const unsigned* pdst = packed + (size_t)(BB + b) * WPI;

    // stage weight table
    for (int i = t; i < WTABN / 4; i += 256)
        ((float4*)wtab)[i] = ((const float4*)wtab_g)[i];
    // stage bitmask halos
    for (int i = t; i < 74 * 4; i += 256) {
        int r = i >> 2, w = (i & 3) + 1;
        int gy = ty0 - 22 + r, gw = wb0 + (w - 1);
        sSrc[r][w] = (gy >= 0 && gy < HH && gw >= 0 && gw < 32) ? psrc[(gy << 5) + gw] : 0u;
    }
    for (int i = t; i < 78 * 4; i += 256) {
        int r = i >> 2, w = (i & 3) + 1;
        int gy = ty0 - 23 + r, gw = wb0 + (w - 1);
        sDst[r][w] = (gy >= 0 && gy < HH && gw >= 0 && gw < 32) ? pdst[(gy << 5) + gw] : 0u;
    }
    if (t < 78) { sDst[t][0] = 0; sDst[t][5] = 0; if (t < 74) { sSrc[t][0] = 0; sSrc[t][5] = 0; } }
    if (t < NQ) {
        int dx = (int)xx[t], dy = (int)yy[t];
        prank[(dy + 3) * 15 + (dx + 7)] = (t << 8) | ((dx + 7) << 4) | (dy + 3);
    }
    ((unsigned*)sVB)[t] = 0; ((unsigned*)sVB)[t + 256] = 0;
    if (t == 0) lcnt = 0;
    __syncthreads();

    // Phase A: bit-parallel kept/found over 72 candidate rows x 4 words
    for (int task = t; task < 288; task += 256) {
        int cr = task >> 2, w = (task & 3) + 1;
        unsigned C = sSrc[cr + 2][w];
        unsigned found = 0;
        if (C) {
            #define EXT5(row) ( (u64)((row)[w-1] >> 30) \
                              | ((u64)(row)[w] << 2) \
                              | ((u64)((row)[w+1] & 3u) << 34) )
            u64 a = EXT5(sSrc[cr]) | EXT5(sSrc[cr + 1]);
            u64 or5 = a | (a >> 1) | (a >> 2) | (a >> 3) | (a >> 4);
            u64 e2 = EXT5(sSrc[cr + 2]);
            unsigned kept = C & ~(unsigned)(or5 | e2 | (e2 >> 1));
            if (kept) {
                u64 dil = 0;
                #pragma unroll
                for (int rr = 0; rr < 7; ++rr) {
                    const unsigned* row = sDst[cr + rr];
                    dil |= (u64)(row[w-1] >> 25) | ((u64)row[w] << 7)
                         | ((u64)(row[w+1] & 0x7Fu) << 39);
                }
                u64 a2 = dil | (dil >> 1);
                u64 b2 = a2 | (a2 >> 2);
                u64 c2 = b2 | (b2 >> 4);
                u64 o15 = c2 | (c2 >> 7);
                found = kept & (unsigned)o15;
            }
        }
        if (w == 1) found &= 0xFFFFF000u;    // px >= tx0-20
        if (w == 4) found &= 0x000FFFFFu;    // px <= tx0+83
        if (found) {
            int nf = __popc(found);
            int base = atomicAdd(&lcnt, nf);
            unsigned fi = found;
            while (fi) {
                int bit = __builtin_ctz(fi); fi &= fi - 1;
                int px = tx0 - 32 + ((w - 1) << 5) + bit;
                if (base < CAP) sPt[base] = (unsigned)((cr << 10) | px);
                ++base;
            }
        }
    }
    __syncthreads();
    int nPts = lcnt; if (nPts > CAP) nPts = CAP;
    int n4 = (nPts + 3) & ~3;

    // Phase B: per-point nearest-correspondence (minr) + record packing
    if (t < nPts) {
        unsigned e = sPt[t];
        int cr = (int)(e >> 10), px = (int)(e & 1023u);
        int q = px - tx0 + 25;               // bit (px-7) rel. to LDS word0
        int widx = 1 + (q >> 5), sh = q & 31;
        u64 lo = 0, hi = 0;
        #pragma unroll
        for (int rr = 0; rr < 7; ++rr) {
            const unsigned* row = sDst[cr + rr];
            u64 win = (((u64)row[widx] | ((u64)row[widx + 1] << 32)) >> sh) & 0x7FFFull;
            if (rr < 4) lo |= win << (15 * rr);
            else        hi |= win << (15 * (rr - 4));
        }
        int minv = 0x7FFFFFFF;
        while (lo) { int bb2 = __builtin_ctzll(lo); lo &= lo - 1; int rv = prank[bb2];      if (rv < minv) minv = rv; }
        while (hi) { int bb2 = __builtin_ctzll(hi); hi &= hi - 1; int rv = prank[60 + bb2]; if (rv < minv) minv = rv; }
        int vxp7 = (minv >> 4) & 15, vyp3 = minv & 15;
        int py = ty0 - 20 + cr;
        sPt[t] = (unsigned)px | ((unsigned)py << 10)
               | ((unsigned)vxp7 << 19) | ((unsigned)vyp3 << 23);
        if (px >= tx0 && px < tx0 + TLW && cr >= 20 && cr < 20 + TLH)
            sVB[(cr - 20) * TLW + (px - tx0)] =
                (unsigned char)(0x80 | vxp7 | (vyp3 << 4));
    }
    if (t < n4 - nPts) sPt[nPts + t] = 0xFFFFFFFFu;   // py=511 sentinel
    __syncthreads();

    // Phase C: branchless gather-splat (8 px/thread: 4 cols x 2 rows)
    int x0q = tx0 + (t & 15) * 4;
    int y0t = ty0 + (t >> 4) * 2;

    v2f a0p[2][2] = {};          // a0 col-pairs
    v2f av[2][4]  = {};          // (a1,a2) per [ry][col]

    for (int p = 0; p < n4; p += 4) {
        uint4 P = *(const uint4*)&sPt[p];
        #pragma unroll
        for (int k = 0; k < 4; ++k) {
            int spk = __builtin_amdgcn_readfirstlane(
                (int)(k == 0 ? P.x : k == 1 ? P.y : k == 2 ? P.z : P.w));
            int pxp21 = (spk & 1023) + 21;
            int pyp20 = ((spk >> 10) & 511) + 20;
            float pvx = (float)(((spk >> 19) & 15) - 7);
            float pvy = (float)(((spk >> 23) & 7) - 3);
            v2f vv = {pvx, pvy};

            int coff = pxp21 - x0q;
            coff = coff < 0 ? 0 : (coff > 45 ? 45 : coff);
            int rot = coff & 3;
            int cb  = rot * (42 * 48) + (coff & ~3);
            #pragma unroll
            for (int ry = 0; ry < 2; ++ry) {
                int dyr = pyp20 - (y0t + ry);
                int rowi = ((unsigned)dyr > 40u) ? 41 : dyr;  // row 41 = zeros
                float4 wv = *(const float4*)&wtab[cb + rowi * 48];
                a0p[ry][0] += (v2f){wv.w, wv.z};
                a0p[ry][1] += (v2f){wv.y, wv.x};
                av[ry][0] += wv.w * vv;
                av[ry][1] += wv.z * vv;
                av[ry][2] += wv.y * vv;
                av[ry][3] += wv.x * vv;
            }
        }
    }

    // Epilogue: all 6 planes, branchless, fully coalesced float4
    size_t bbase = (size_t)b * HH * WW;
    int lx = x0q - tx0;
    #pragma unroll
    for (int ry = 0; ry < 2; ++ry) {
        int y = y0t + ry;
        int ly = y - ty0;
        unsigned vb4 = *(const unsigned*)&sVB[ly * TLW + lx];
        size_t idx = bbase + (size_t)y * WW + x0q;
        float d0 = a0p[ry][0].x + 1.6f, d1 = a0p[ry][0].y + 1.6f;
        float d2 = a0p[ry][1].x + 1.6f, d3 = a0p[ry][1].y + 1.6f;
        float4 ox = { (float)x0q     + av[ry][0].x / d0, (float)(x0q+1) + av[ry][1].x / d1,
                      (float)(x0q+2) + av[ry][2].x / d2, (float)(x0q+3) + av[ry][3].x / d3 };
        float4 oy = { (float)y + av[ry][0].y / d0, (float)y + av[ry][1].y / d1,
                      (float)y + av[ry][2].y / d2, (float)y + av[ry][3].y / d3 };
        float4 o2, o3, o4, o5;
        float* po2 = &o2.x; float* po3 = &o3.x; float* po4 = &o4.x; float* po5 = &o5.x;
        #pragma unroll
        for (int jj = 0; jj < 4; ++jj) {
            unsigned by = (vb4 >> (8 * jj)) & 255u;
            float fm  = (float)(by >> 7);
            float fvx = (float)((int)(by & 15u) - 7);
            float fvy = (float)((int)((by >> 4) & 7u) - 3);
            float fx  = (float)(x0q + jj);
            po2[jj] = fx * fm;
            po3[jj] = (float)y * fm;
            po4[jj] = (fx + fvx) * fm;
            po5[jj] = ((float)y + fvy) * fm;
        }
        *reinterpret_cast<float4*>(out + idx)                     = ox;
        *reinterpret_cast<float4*>(out + (size_t)N_PIX + idx)     = oy;
        *reinterpret_cast<float4*>(out + 2 * (size_t)N_PIX + idx) = o2;
        *reinterpret_cast<float4*>(out + 3 * (size_t)N_PIX + idx) = o3;
        *reinterpret_cast<float4*>(out + 4 * (size_t)N_PIX + idx) = o4;
        *reinterpret_cast<float4*>(out + 5 * (size_t)N_PIX + idx) = o5;
    }
}

extern "C" void kernel_launch(void* const* d_in, const int* in_sizes, int n_in,
                              void* d_out, int out_size, void* d_ws, size_t ws_size,
                              hipStream_t stream) {
    const float* src = (const float*)d_in[0];
    const float* dst = (const float*)d_in[1];
    const float* xx  = (const float*)d_in[2];
    const float* yy  = (const float*)d_in[3];
    float* out = (float*)d_out;

    unsigned* packed = (unsigned*)d_ws;
    float*    wtab_g = (float*)((char*)d_ws + WTAB_OFF);

    pack_zero<<<(2 * N_PIX / 4) / 256, 256, 0, stream>>>(src, dst, packed, wtab_g);

    dim3 g2(TXN, TYN, BB);
    fused_morph<<<g2, 256, 0, stream>>>(packed, xx, yy, wtab_g, out);
}

// Round 8
// 124.556 us; speedup vs baseline: 1.1250x; 1.1250x over previous
//
#include <hip/hip_runtime.h>

// BNMorph forward — fused per-tile point re-derivation + wave-compacted splat.
// B=8, H=320, W=1024. Outputs (concat, f32, each [B,H,W]):
//   0 morphedx, 1 morphedy, 2 orgpts_x, 3 orgpts_y, 4 correspts_x, 5 correspts_y

#define BB 8
#define HH 320
#define WW 1024
#define N_PIX (BB*HH*WW)            // 2,621,440
#define WPI (HH*(WW/32))            // 10240 words per image
#define RR 20
#define TLW 64
#define TLH 32
#define TXN (WW/TLW)                // 16
#define TYN (HH/TLH)                // 10
#define NQ 105
#define CAP 192                     // per-tile candidate capacity (mean ~103)
#define WSTRIDE 52                  // wtab row stride (52 mod 32 = 20; 2 rows -> 8-bank shift)
#define WTABN (2*42*WSTRIDE)        // 4368 floats, 2 rotation copies
#define WTAB_OFF (2*BB*WPI*4)       // 655360 (16B aligned)

typedef unsigned long long u64;
typedef float v2f __attribute__((ext_vector_type(2)));

// ---- kernel 1: pack maps to bitmasks + build 2-rotation weight table ----
__global__ __launch_bounds__(256) void pack_zero(
    const float* __restrict__ src, const float* __restrict__ dst,
    unsigned* __restrict__ packed, float* __restrict__ wtab_g)
{
    int t = threadIdx.x;
    int i = blockIdx.x * 256 + t;           // float4 index in [0, 2*N_PIX/4)
    if (i < WTABN) {                        // copy rot stores at col c: weight for pc=c+rot
        int rot = i / (42 * WSTRIDE);
        int rem = i - rot * (42 * WSTRIDE);
        int row = rem / WSTRIDE, c = rem - row * WSTRIDE;
        int pc = c + rot;
        float v = 0.0f;
        if (row <= 40 && pc >= 4 && pc <= 44) {
            int dxv = pc - 24, dyv = row - 20;
            float d = sqrtf((float)(dxv * dxv + dyv * dyv));
            v = 0.7f * expf((-d * 1.9f) / 24.0f);
        }
        wtab_g[i] = v;
    }
    const float4* p = (i < (N_PIX >> 2)) ? (const float4*)src + i
                                         : (const float4*)dst + (i - (N_PIX >> 2));
    float4 v = *p;
    unsigned nib = (v.x > 0.5f ? 1u : 0u) | (v.y > 0.5f ? 2u : 0u)
                 | (v.z > 0.5f ? 4u : 0u) | (v.w > 0.5f ? 8u : 0u);
    unsigned val = nib << ((t & 7) * 4);
    val |= __shfl_xor(val, 1);
    val |= __shfl_xor(val, 2);
    val |= __shfl_xor(val, 4);
    if ((t & 7) == 0) packed[i >> 3] = val;
}

// ---- kernel 2: fused point-finding + wave-compacted splat, 64x32 tiles ----
__global__ __launch_bounds__(256, 5) void fused_morph(
    const unsigned* __restrict__ packed,
    const float* __restrict__ xx, const float* __restrict__ yy,
    const float* __restrict__ wtab_g,
    float* __restrict__ out)
{
    __shared__ __align__(16) float wtab[WTABN];      // 17.06 KB
    __shared__ unsigned sSrc[74][6];   // rows ty0-22..ty0+51, pads at word 0,5
    __shared__ unsigned sDst[78][6];   // rows ty0-23..ty0+54
    __shared__ __align__(16) unsigned sPt[CAP];
    __shared__ __align__(16) unsigned sWav[4][200];  // per-wave filtered lists
    __shared__ int prank[NQ];          // window pos -> (rank<<8)|((dx+7)<<4)|(dy+3)
    __shared__ unsigned char sVB[TLH * TLW];         // in-tile 0x80|vxp7|(vyp3<<4)
    __shared__ int lcnt;

    int t = threadIdx.x;
    int txT = blockIdx.x, tyT = blockIdx.y, b = blockIdx.z;
    int tx0 = txT * TLW, ty0 = tyT * TLH;
    int wb0 = (tx0 >> 5) - 1;
    const unsigned* psrc = packed + (size_t)b * WPI;
    const unsigned* pdst = packed + (size_t)(BB + b) * WPI;

    // stage weight table (1092 float4)
    for (int i = t; i < WTABN / 4; i += 256)
        ((float4*)wtab)[i] = ((const float4*)wtab_g)[i];
    // stage bitmask halos
    for (int i = t; i < 74 * 4; i += 256) {
        int r = i >> 2, w = (i & 3) + 1;
        int gy = ty0 - 22 + r, gw = wb0 + (w - 1);
        sSrc[r][w] = (gy >= 0 && gy < HH && gw >= 0 && gw < 32) ? psrc[(gy << 5) + gw] : 0u;
    }
    for (int i = t; i < 78 * 4; i += 256) {
        int r = i >> 2, w = (i & 3) + 1;
        int gy = ty0 - 23 + r, gw = wb0 + (w - 1);
        sDst[r][w] = (gy >= 0 && gy < HH && gw >= 0 && gw < 32) ? pdst[(gy << 5) + gw] : 0u;
    }
    if (t < 78) { sDst[t][0] = 0; sDst[t][5] = 0; if (t < 74) { sSrc[t][0] = 0; sSrc[t][5] = 0; } }
    if (t < NQ) {
        int dx = (int)xx[t], dy = (int)yy[t];
        prank[(dy + 3) * 15 + (dx + 7)] = (t << 8) | ((dx + 7) << 4) | (dy + 3);
    }
    ((unsigned*)sVB)[t] = 0; ((unsigned*)sVB)[t + 256] = 0;
    if (t == 0) lcnt = 0;
    __syncthreads();

    // Phase A: bit-parallel kept/found over 72 candidate rows x 4 words
    for (int task = t; task < 288; task += 256) {
        int cr = task >> 2, w = (task & 3) + 1;
        unsigned C = sSrc[cr + 2][w];
        unsigned found = 0;
        if (C) {
            #define EXT5(row) ( (u64)((row)[w-1] >> 30) \
                              | ((u64)(row)[w] << 2) \
                              | ((u64)((row)[w+1] & 3u) << 34) )
            u64 a = EXT5(sSrc[cr]) | EXT5(sSrc[cr + 1]);
            u64 or5 = a | (a >> 1) | (a >> 2) | (a >> 3) | (a >> 4);
            u64 e2 = EXT5(sSrc[cr + 2]);
            unsigned kept = C & ~(unsigned)(or5 | e2 | (e2 >> 1));
            if (kept) {
                u64 dil = 0;
                #pragma unroll
                for (int rr = 0; rr < 7; ++rr) {
                    const unsigned* row = sDst[cr + rr];
                    dil |= (u64)(row[w-1] >> 25) | ((u64)row[w] << 7)
                         | ((u64)(row[w+1] & 0x7Fu) << 39);
                }
                u64 a2 = dil | (dil >> 1);
                u64 b2 = a2 | (a2 >> 2);
                u64 c2 = b2 | (b2 >> 4);
                u64 o15 = c2 | (c2 >> 7);
                found = kept & (unsigned)o15;
            }
        }
        if (w == 1) found &= 0xFFFFF000u;    // px >= tx0-20
        if (w == 4) found &= 0x000FFFFFu;    // px <= tx0+83
        if (found) {
            int nf = __popc(found);
            int base = atomicAdd(&lcnt, nf);
            unsigned fi = found;
            while (fi) {
                int bit = __builtin_ctz(fi); fi &= fi - 1;
                int px = tx0 - 32 + ((w - 1) << 5) + bit;
                if (base < CAP) sPt[base] = (unsigned)((cr << 10) | px);
                ++base;
            }
        }
    }
    __syncthreads();
    int nPts = lcnt; if (nPts > CAP) nPts = CAP;

    // Phase B: per-point nearest-correspondence (minr) + record packing
    if (t < nPts) {
        unsigned e = sPt[t];
        int cr = (int)(e >> 10), px = (int)(e & 1023u);
        int q = px - tx0 + 25;               // bit (px-7) rel. to LDS word0
        int widx = 1 + (q >> 5), sh = q & 31;
        u64 lo = 0, hi = 0;
        #pragma unroll
        for (int rr = 0; rr < 7; ++rr) {
            const unsigned* row = sDst[cr + rr];
            u64 win = (((u64)row[widx] | ((u64)row[widx + 1] << 32)) >> sh) & 0x7FFFull;
            if (rr < 4) lo |= win << (15 * rr);
            else        hi |= win << (15 * (rr - 4));
        }
        int minv = 0x7FFFFFFF;
        while (lo) { int bb2 = __builtin_ctzll(lo); lo &= lo - 1; int rv = prank[bb2];      if (rv < minv) minv = rv; }
        while (hi) { int bb2 = __builtin_ctzll(hi); hi &= hi - 1; int rv = prank[60 + bb2]; if (rv < minv) minv = rv; }
        int vxp7 = (minv >> 4) & 15, vyp3 = minv & 15;
        int py = ty0 - 20 + cr;
        sPt[t] = (unsigned)px | ((unsigned)py << 10)
               | ((unsigned)vxp7 << 19) | ((unsigned)vyp3 << 23);
        if (px >= tx0 && px < tx0 + TLW && cr >= 20 && cr < 20 + TLH)
            sVB[(cr - 20) * TLW + (px - tx0)] =
                (unsigned char)(0x80 | vxp7 | (vyp3 << 4));
    }
    __syncthreads();

    // Per-wave y-strip compaction (wave-local, no extra barrier needed)
    int lane = t & 63, w = __builtin_amdgcn_readfirstlane(t >> 6);
    int wy0 = ty0 + w * 8;                   // wave strip rows [wy0, wy0+7]
    int cw = 0;
    for (int base = 0; base < nPts; base += 64) {
        int i = base + lane;
        unsigned pk = (i < nPts) ? sPt[i] : 0xFFFFFFFFu;
        int py = (int)((pk >> 10) & 511u);
        bool pass = (i < nPts) & (py >= wy0 - 20) & (py <= wy0 + 27);
        u64 m = __ballot(pass);
        if (pass) {
            int idx = __popcll(m & ((1ull << lane) - 1ull));
            sWav[w][cw + idx] = pk;
        }
        cw += __popcll(m);
    }
    int c4 = (cw + 3) & ~3;
    if (lane < c4 - cw) sWav[w][cw + lane] = 0xFFFFFFFFu;   // py=511 sentinel

    // Phase C: branchless gather-splat (8 px/thread: 4 cols x 2 rows)
    int x0q = tx0 + (t & 15) * 4;
    int y0t = ty0 + (t >> 4) * 2;

    v2f a0p[2][2] = {};          // a0 col-pairs
    v2f av[2][4]  = {};          // (a1,a2) per [ry][col]

    for (int p = 0; p < c4; p += 4) {
        uint4 P = *(const uint4*)&sWav[w][p];
        #pragma unroll
        for (int k = 0; k < 4; ++k) {
            int spk = __builtin_amdgcn_readfirstlane(
                (int)(k == 0 ? P.x : k == 1 ? P.y : k == 2 ? P.z : P.w));
            int pxp21 = (spk & 1023) + 21;
            int pyp20 = ((spk >> 10) & 511) + 20;
            float pvx = (float)(((spk >> 19) & 15) - 7);
            float pvy = (float)(((spk >> 23) & 7) - 3);
            v2f vv = {pvx, pvy};

            int coff = pxp21 - x0q;                      // col3's padded idx
            coff = coff < 0 ? 0 : (coff > 45 ? 45 : coff);
            int rot = coff & 1;                          // scalar (coff lane-delta = 4)
            int cb  = rot * (42 * WSTRIDE) + (coff & ~1);
            #pragma unroll
            for (int ry = 0; ry < 2; ++ry) {
                int dyr = pyp20 - (y0t + ry);
                int rowi = ((unsigned)dyr > 40u) ? 41 : dyr;  // row 41 = zeros
                const float* wr = &wtab[cb + rowi * WSTRIDE];
                v2f w01 = *(const v2f*)wr;       // pc coff, coff+1  (col3, col2)
                v2f w23 = *(const v2f*)(wr + 2); // pc coff+2, coff+3 (col1, col0)
                a0p[ry][0] += (v2f){w23.y, w23.x};
                a0p[ry][1] += (v2f){w01.y, w01.x};
                av[ry][0] += w23.y * vv;
                av[ry][1] += w23.x * vv;
                av[ry][2] += w01.y * vv;
                av[ry][3] += w01.x * vv;
            }
        }
    }

    // Epilogue: all 6 planes, branchless, fully coalesced float4
    size_t bbase = (size_t)b * HH * WW;
    int lx = x0q - tx0;
    #pragma unroll
    for (int ry = 0; ry < 2; ++ry) {
        int y = y0t + ry;
        int ly = y - ty0;
        unsigned vb4 = *(const unsigned*)&sVB[ly * TLW + lx];
        size_t idx = bbase + (size_t)y * WW + x0q;
        float d0 = a0p[ry][0].x + 1.6f, d1 = a0p[ry][0].y + 1.6f;
        float d2 = a0p[ry][1].x + 1.6f, d3 = a0p[ry][1].y + 1.6f;
        float4 ox = { (float)x0q     + av[ry][0].x / d0, (float)(x0q+1) + av[ry][1].x / d1,
                      (float)(x0q+2) + av[ry][2].x / d2, (float)(x0q+3) + av[ry][3].x / d3 };
        float4 oy = { (float)y + av[ry][0].y / d0, (float)y + av[ry][1].y / d1,
                      (float)y + av[ry][2].y / d2, (float)y + av[ry][3].y / d3 };
        float4 o2, o3, o4, o5;
        float* po2 = &o2.x; float* po3 = &o3.x; float* po4 = &o4.x; float* po5 = &o5.x;
        #pragma unroll
        for (int jj = 0; jj < 4; ++jj) {
            unsigned by = (vb4 >> (8 * jj)) & 255u;
            float fm  = (float)(by >> 7);
            float fvx = (float)((int)(by & 15u) - 7);
            float fvy = (float)((int)((by >> 4) & 7u) - 3);
            float fx  = (float)(x0q + jj);
            po2[jj] = fx * fm;
            po3[jj] = (float)y * fm;
            po4[jj] = (fx + fvx) * fm;
            po5[jj] = ((float)y + fvy) * fm;
        }
        *reinterpret_cast<float4*>(out + idx)                     = ox;
        *reinterpret_cast<float4*>(out + (size_t)N_PIX + idx)     = oy;
        *reinterpret_cast<float4*>(out + 2 * (size_t)N_PIX + idx) = o2;
        *reinterpret_cast<float4*>(out + 3 * (size_t)N_PIX + idx) = o3;
        *reinterpret_cast<float4*>(out + 4 * (size_t)N_PIX + idx) = o4;
        *reinterpret_cast<float4*>(out + 5 * (size_t)N_PIX + idx) = o5;
    }
}

extern "C" void kernel_launch(void* const* d_in, const int* in_sizes, int n_in,
                              void* d_out, int out_size, void* d_ws, size_t ws_size,
                              hipStream_t stream) {
    const float* src = (const float*)d_in[0];
    const float* dst = (const float*)d_in[1];
    const float* xx  = (const float*)d_in[2];
    const float* yy  = (const float*)d_in[3];
    float* out = (float*)d_out;

    unsigned* packed = (unsigned*)d_ws;
    float*    wtab_g = (float*)((char*)d_ws + WTAB_OFF);

    pack_zero<<<(2 * N_PIX / 4) / 256, 256, 0, stream>>>(src, dst, packed, wtab_g);

    dim3 g2(TXN, TYN, BB);
    fused_morph<<<g2, 256, 0, stream>>>(packed, xx, yy, wtab_g, out);
}